// Round 12
// baseline (42.584 us; speedup 1.0000x reference)
//
#include <hip/hip_runtime.h>
#include <math.h>

#define HS    200   // HIST_SIZE
#define DIMV  64    // DIM
#define HID   32    // HIDDEN
#define NTH   512
#define NB    4     // batches per block (pipelined)

typedef __attribute__((ext_vector_type(8))) short short8;   // 8 bf16 (4 VGPRs)
typedef __attribute__((ext_vector_type(4))) float f32x4;    // MFMA acc
typedef __bf16 bf2_t __attribute__((ext_vector_type(2)));
typedef float  f2_t  __attribute__((ext_vector_type(2)));

// packed f32x2 -> bf16x2 (RNE) -> v_cvt_pk_bf16_f32
__device__ __forceinline__ unsigned cvt2(float x, float y) {
    f2_t f = {x, y};
    bf2_t bv = __builtin_convertvector(f, bf2_t);
    union { bf2_t b; unsigned u; } un;
    un.b = bv;
    return un.u;
}
__device__ __forceinline__ float bf16f(short x) {
    return __uint_as_float(((unsigned)(unsigned short)x) << 16);
}

// DPP cross-lane (VALU pipe, no lgkmcnt)
template<int CTRL>
__device__ __forceinline__ float dpp_add(float x) {
    int y = __builtin_amdgcn_update_dpp(0, __float_as_int(x), CTRL, 0xF, 0xF, true);
    return x + __int_as_float(y);
}
template<int CTRL>
__device__ __forceinline__ float dpp_max(float x) {
    int y = __builtin_amdgcn_update_dpp(0, __float_as_int(x), CTRL, 0xF, 0xF, true);
    return fmaxf(x, __int_as_float(y));
}
#define ROR1  0x121
#define ROR2  0x122
#define ROR4  0x124
#define ROR8  0x128
#define QXOR1 0xB1   // quad_perm [1,0,3,2]
#define QXOR2 0x4E   // quad_perm [2,3,0,1]
#define HMIRR 0x141  // row_half_mirror
__device__ __forceinline__ float swz_xor16(float x) {  // lane ^ 16 (within 32)
    return __int_as_float(__builtin_amdgcn_ds_swizzle(__float_as_int(x), 0x401F));
}

// s_h: 208 rows x 64 ushort (128 B/row). 16-B groups XOR-swizzled by (row&7).
// s_Mt: double-buffered 32 x 64 ushort, same swizzle.

__global__ __launch_bounds__(NTH, 4) void din_attn_kernel(
    const float* __restrict__ cand,   // B x 64
    const float* __restrict__ hist,   // B x 200 x 64
    const int*   __restrict__ lens,   // B
    const float* __restrict__ W1,     // 256 x 32
    const float* __restrict__ B1,     // 32
    const float* __restrict__ W2,     // 32
    const float* __restrict__ B2,     // 1 (uniform shift cancels in softmax)
    float* __restrict__ out)          // B x 64
{
    __shared__ __align__(16) unsigned short s_h[208 * 64];      // 26624 B
    __shared__ __align__(16) unsigned short s_Mt[2][HID * 64];  // 8192 B
    __shared__ float s_sc[208];          // 832 B
    __shared__ float s_c[2][HID];        // 256 B
    __shared__ float s_w2[HID];          // 128 B
    __shared__ __align__(16) float s_part[8 * DIMV];  // 2048 B -> ~37.2 KB

    const int tid  = threadIdx.x;
    const int lane = tid & 63, wid = tid >> 6;
    const int GRID = gridDim.x;

    // ---- hoisted loop-invariant W1 registers (role split, wave-uniform) --------
    const int h_m = tid & 31, fg_m = tid >> 5;        // Mt-build role (tid<256)
    const int t2  = tid - 256;
    const int h_c = t2 >> 3, fg_c = t2 & 7;           // c-build role (tid>=256)
    float wbd[8], wcc[8];   // tid<256:  Wb-Wd, Wc
    float wad[8];           // tid>=256: Wa+Wd
    float b1h = 0.f;
    if (tid < 256) {
        #pragma unroll
        for (int ff = 0; ff < 8; ++ff) {
            int f = fg_m * 8 + ff;
            wbd[ff] = W1[(DIMV + f) * HID + h_m] - W1[(3 * DIMV + f) * HID + h_m];
            wcc[ff] = W1[(2 * DIMV + f) * HID + h_m];
        }
        if (tid < HID) s_w2[tid] = W2[tid];
    } else {
        #pragma unroll
        for (int ff = 0; ff < 8; ++ff) {
            int f = fg_c * 8 + ff;
            wad[ff] = W1[f * HID + h_c] + W1[(3 * DIMV + f) * HID + h_c];
        }
        b1h = B1[h_c];
    }

    int lenk[NB];
    #pragma unroll
    for (int k = 0; k < NB; ++k) lenk[k] = lens[blockIdx.x + k * GRID];

    float4 va[4], vb[4];   // hist prefetch registers (issue-early / write-late)

    auto issueLoads = [&](int b, int npairs) {
        const float4* hp = (const float4*)(hist + (size_t)b * (HS * DIMV));
        #pragma unroll
        for (int j = 0; j < 4; ++j) {
            int pi = tid + j * NTH;
            if (pi < npairs) { va[j] = hp[2 * pi]; vb[j] = hp[2 * pi + 1]; }
        }
    };
    auto writeLDS = [&](int npairs) {
        #pragma unroll
        for (int j = 0; j < 4; ++j) {
            int pi = tid + j * NTH;
            if (pi < npairs) {
                int r = pi >> 3, g = pi & 7;
                int pg = g ^ (r & 7);
                uint4 w = make_uint4(cvt2(va[j].x, va[j].y), cvt2(va[j].z, va[j].w),
                                     cvt2(vb[j].x, vb[j].y), cvt2(vb[j].z, vb[j].w));
                *(uint4*)&s_h[r * 64 + pg * 8] = w;
            }
        }
    };
    auto phaseA = [&](int b, int bi) {   // per-batch M (bf16, swizzled) and c
        const float* cbk = cand + (size_t)b * DIMV;
        if (tid < 256) {
            float4 cA = *(const float4*)(cbk + fg_m * 8);
            float4 cB = *(const float4*)(cbk + fg_m * 8 + 4);
            float cf[8] = {cA.x, cA.y, cA.z, cA.w, cB.x, cB.y, cB.z, cB.w};
            float m[8];
            #pragma unroll
            for (int ff = 0; ff < 8; ++ff) m[ff] = fmaf(cf[ff], wcc[ff], wbd[ff]);
            uint4 mw = make_uint4(cvt2(m[0], m[1]), cvt2(m[2], m[3]),
                                  cvt2(m[4], m[5]), cvt2(m[6], m[7]));
            int pg = fg_m ^ (h_m & 7);
            *(uint4*)&s_Mt[bi][h_m * 64 + pg * 8] = mw;
        } else {
            float4 cA = *(const float4*)(cbk + fg_c * 8);
            float4 cB = *(const float4*)(cbk + fg_c * 8 + 4);
            float cf[8] = {cA.x, cA.y, cA.z, cA.w, cB.x, cB.y, cB.z, cB.w};
            float p = 0.f;
            #pragma unroll
            for (int ff = 0; ff < 8; ++ff) p = fmaf(cf[ff], wad[ff], p);
            p = dpp_add<QXOR1>(p);
            p = dpp_add<QXOR2>(p);
            p = dpp_add<HMIRR>(p);
            if ((t2 & 7) == 0) s_c[bi][h_c] = p + b1h;
        }
    };

    // ---------------- prologue: batch 0 ----------------------------------------
    {
        int len0  = lenk[0];
        int nrow0 = (len0 == 0) ? HS : len0;
        issueLoads(blockIdx.x, nrow0 * 8);
        phaseA(blockIdx.x, 0);
        writeLDS(nrow0 * 8);                 // vmcnt wait lands here
    }
    __syncthreads();

    // ---------------- pipelined main loop ---------------------------------------
    #pragma unroll
    for (int k = 0; k < NB; ++k) {
        const int b    = blockIdx.x + k * GRID;
        const int len  = lenk[k];
        const int nrow = (len == 0) ? HS : len;
        const int kn   = k + 1;
        int nrown = 0;
        if (kn < NB) {                       // issue next batch's loads EARLY
            int lenn = lenk[kn];
            nrown = (lenn == 0) ? HS : lenn;
            issueLoads(blockIdx.x + kn * GRID, nrown * 8);
        }

        // ---- P1(k): scores via MFMA over ceil(len/16) tiles ----
        {
            const int nt = (len + 15) >> 4;
            const int lc = lane & 15, lg = lane >> 4;
            const float c0  = s_c[k & 1][lc],  c1  = s_c[k & 1][16 + lc];
            const float w20 = s_w2[lc],        w21 = s_w2[16 + lc];
            const unsigned short* mt = s_Mt[k & 1];
            short8 b00 = *(const short8*)&mt[lc * 64        + ((lg)     ^ (lc & 7)) * 8];
            short8 b01 = *(const short8*)&mt[lc * 64        + ((4 + lg) ^ (lc & 7)) * 8];
            short8 b10 = *(const short8*)&mt[(16 + lc) * 64 + ((lg)     ^ (lc & 7)) * 8];
            short8 b11 = *(const short8*)&mt[(16 + lc) * 64 + ((4 + lg) ^ (lc & 7)) * 8];

            for (int rt = wid; rt < nt; rt += 8) {
                int s = rt * 16 + lc;
                s = (s < len) ? s : (len - 1);
                short8 a0 = *(const short8*)&s_h[s * 64 + ((lg)     ^ (s & 7)) * 8];
                short8 a1 = *(const short8*)&s_h[s * 64 + ((4 + lg) ^ (s & 7)) * 8];
                f32x4 acc0 = {c0, c0, c0, c0};
                acc0 = __builtin_amdgcn_mfma_f32_16x16x32_bf16(a0, b00, acc0, 0, 0, 0);
                acc0 = __builtin_amdgcn_mfma_f32_16x16x32_bf16(a1, b01, acc0, 0, 0, 0);
                f32x4 acc1 = {c1, c1, c1, c1};
                acc1 = __builtin_amdgcn_mfma_f32_16x16x32_bf16(a0, b10, acc1, 0, 0, 0);
                acc1 = __builtin_amdgcn_mfma_f32_16x16x32_bf16(a1, b11, acc1, 0, 0, 0);
                float p[4];
                #pragma unroll
                for (int r = 0; r < 4; ++r)
                    p[r] = fmaxf(acc0[r], 0.f) * w20 + fmaxf(acc1[r], 0.f) * w21;
                #pragma unroll
                for (int r = 0; r < 4; ++r) {
                    p[r] = dpp_add<ROR1>(p[r]);
                    p[r] = dpp_add<ROR2>(p[r]);
                    p[r] = dpp_add<ROR4>(p[r]);
                    p[r] = dpp_add<ROR8>(p[r]);
                }
                if (lc == 0) {
                    int rbase = rt * 16 + lg * 4;
                    #pragma unroll
                    for (int r = 0; r < 4; ++r) s_sc[rbase + r] = p[r];
                }
            }
        }
        if (kn < NB) phaseA(blockIdx.x + kn * GRID, kn & 1);  // overlaps P1 latency
        __syncthreads();

        // ---- P2(k): softmax by wave 0 (weights = e*inv stored in s_sc) ----
        if (wid == 0) {
            float xs[4];
            #pragma unroll
            for (int j = 0; j < 4; ++j) {
                int s = j * 64 + lane;
                if (len == 0) xs[j] = (s < HS) ? 0.f : -INFINITY;
                else          xs[j] = (s < len) ? s_sc[s] * 0.125f : -INFINITY;
            }
            float mx = fmaxf(fmaxf(xs[0], xs[1]), fmaxf(xs[2], xs[3]));
            mx = dpp_max<ROR1>(mx); mx = dpp_max<ROR2>(mx);
            mx = dpp_max<ROR4>(mx); mx = dpp_max<ROR8>(mx);
            mx = fmaxf(mx, swz_xor16(mx));
            mx = fmaxf(mx, __shfl_xor(mx, 32));
            float e[4];
            float sm = 0.f;
            #pragma unroll
            for (int j = 0; j < 4; ++j) { e[j] = __expf(xs[j] - mx); sm += e[j]; }
            sm = dpp_add<ROR1>(sm); sm = dpp_add<ROR2>(sm);
            sm = dpp_add<ROR4>(sm); sm = dpp_add<ROR8>(sm);
            sm += swz_xor16(sm);
            sm += __shfl_xor(sm, 32);
            const float inv = 1.0f / sm;
            #pragma unroll
            for (int j = 0; j < 4; ++j) {
                int s = j * 64 + lane;
                if (s < HS) s_sc[s] = e[j] * inv;
            }
        }
        __syncthreads();

        // ---- P3(k): weighted sum over nrow rows ----
        {
            const int nrb = (nrow + 7) >> 3;
            float a3[8] = {0.f, 0.f, 0.f, 0.f, 0.f, 0.f, 0.f, 0.f};
            for (int rb = wid; rb < nrb; rb += 8) {
                int s = rb * 8 + (lane >> 3);
                float wgt = (s < nrow) ? s_sc[s] : 0.f;
                s = (s < nrow) ? s : (nrow - 1);
                int g = lane & 7;
                short8 hv = *(const short8*)&s_h[s * 64 + (g ^ (s & 7)) * 8];
                #pragma unroll
                for (int j = 0; j < 8; ++j) a3[j] = fmaf(wgt, bf16f(hv[j]), a3[j]);
            }
            #pragma unroll
            for (int j = 0; j < 8; ++j) {
                float x = dpp_add<ROR8>(a3[j]);
                x += swz_xor16(x);
                x += __shfl_xor(x, 32);
                a3[j] = x;
            }
            if (lane < 8) {
                float* dst = &s_part[wid * 64 + lane * 8];
                *(float4*)dst       = make_float4(a3[0], a3[1], a3[2], a3[3]);
                *(float4*)(dst + 4) = make_float4(a3[4], a3[5], a3[6], a3[7]);
            }
        }
        __syncthreads();                     // s_h now free

        if (kn < NB) writeLDS(nrown * 8);    // stage next batch (vmcnt wait here)
        if (tid < DIMV) {                    // epilogue for batch k
            float res = 0.f;
            #pragma unroll
            for (int q = 0; q < 8; ++q) res += s_part[q * 64 + tid];
            out[(size_t)b * DIMV + tid] = res;
        }
        __syncthreads();
    }
}

extern "C" void kernel_launch(void* const* d_in, const int* in_sizes, int n_in,
                              void* d_out, int out_size, void* d_ws, size_t ws_size,
                              hipStream_t stream) {
    const float* cand = (const float*)d_in[0];
    const float* hist = (const float*)d_in[1];
    const int*   lens = (const int*)d_in[2];
    const float* W1   = (const float*)d_in[3];
    const float* B1   = (const float*)d_in[4];
    const float* W2   = (const float*)d_in[5];
    const float* B2   = (const float*)d_in[6];
    float* out = (float*)d_out;

    const int B = in_sizes[0] / DIMV;  // 4096
    const int GRID = B / NB;           // 1024 blocks, each pipelines NB batches
    din_attn_kernel<<<GRID, NTH, 0, stream>>>(cand, hist, lens, W1, B1, W2, B2, out);
}

// Round 13
// 32.682 us; speedup vs baseline: 1.3030x; 1.3030x over previous
//
#include <hip/hip_runtime.h>
#include <math.h>

#define HS    200   // HIST_SIZE
#define DIMV  64    // DIM
#define HID   32    // HIDDEN
#define NTH   256
#define NBPB  4     // batches per block == waves per block (wave-per-batch)

typedef __attribute__((ext_vector_type(8))) short short8;   // 8 bf16 (4 VGPRs)
typedef __attribute__((ext_vector_type(4))) float f32x4;    // MFMA acc
typedef __bf16 bf2_t __attribute__((ext_vector_type(2)));
typedef float  f2_t  __attribute__((ext_vector_type(2)));

// packed f32x2 -> bf16x2 (RNE) -> v_cvt_pk_bf16_f32
__device__ __forceinline__ unsigned cvt2(float x, float y) {
    f2_t f = {x, y};
    bf2_t bv = __builtin_convertvector(f, bf2_t);
    union { bf2_t b; unsigned u; } un;
    un.b = bv;
    return un.u;
}

// DPP cross-lane (VALU pipe, no lgkmcnt)
template<int CTRL>
__device__ __forceinline__ float dpp_add(float x) {
    int y = __builtin_amdgcn_update_dpp(0, __float_as_int(x), CTRL, 0xF, 0xF, true);
    return x + __int_as_float(y);
}
#define ROR1  0x121
#define ROR2  0x122
#define ROR4  0x124
#define ROR8  0x128
#define QXOR1 0xB1   // quad_perm [1,0,3,2]
#define QXOR2 0x4E   // quad_perm [2,3,0,1]
#define HMIRR 0x141  // row_half_mirror (lane ^ 7 within 8)
__device__ __forceinline__ float swz_xor16(float x) {  // lane ^ 16 (within 32)
    return __int_as_float(__builtin_amdgcn_ds_swizzle(__float_as_int(x), 0x401F));
}
__device__ __forceinline__ float rfl(float x) {        // wave-uniform broadcast
    return __int_as_float(__builtin_amdgcn_readfirstlane(__float_as_int(x)));
}

// s_Mt[k]: 32 rows (h) x 64 ushort (f), 16-B groups XOR-swizzled by (h&7).

__global__ __launch_bounds__(NTH, 4) void din_attn_kernel(
    const float* __restrict__ cand,   // B x 64
    const float* __restrict__ hist,   // B x 200 x 64
    const int*   __restrict__ lens,   // B
    const float* __restrict__ W1,     // 256 x 32
    const float* __restrict__ B1,     // 32
    const float* __restrict__ W2,     // 32
    const float* __restrict__ B2,     // 1 (uniform shift cancels in softmax)
    float* __restrict__ out)          // B x 64
{
    __shared__ __align__(16) unsigned short s_Mt[NBPB][HID * 64];  // 16384 B
    __shared__ float s_c[NBPB][HID];                               // 512 B

    const int tid  = threadIdx.x;
    const int lane = tid & 63, wid = tid >> 6;
    const int b0   = blockIdx.x * NBPB;

    // ---------------- Phase A (cooperative, one barrier) ------------------------
    {   // Mt[k][h][f] = bf16(Wb - Wd + cand_k[f]*Wc); W1 slices loaded once
        const int h = tid & 31, fg = tid >> 5;       // f = fg*8 .. fg*8+7
        float wbd[8], wcc[8];
        #pragma unroll
        for (int ff = 0; ff < 8; ++ff) {
            int f = fg * 8 + ff;
            wbd[ff] = W1[(DIMV + f) * HID + h] - W1[(3 * DIMV + f) * HID + h];
            wcc[ff] = W1[(2 * DIMV + f) * HID + h];
        }
        #pragma unroll
        for (int k = 0; k < NBPB; ++k) {
            const float* cb = cand + (size_t)(b0 + k) * DIMV + fg * 8;
            float4 cA = *(const float4*)cb;
            float4 cB = *(const float4*)(cb + 4);
            float cf[8] = {cA.x, cA.y, cA.z, cA.w, cB.x, cB.y, cB.z, cB.w};
            float m[8];
            #pragma unroll
            for (int ff = 0; ff < 8; ++ff) m[ff] = fmaf(cf[ff], wcc[ff], wbd[ff]);
            uint4 mw = make_uint4(cvt2(m[0], m[1]), cvt2(m[2], m[3]),
                                  cvt2(m[4], m[5]), cvt2(m[6], m[7]));
            *(uint4*)&s_Mt[k][h * 64 + (fg ^ (h & 7)) * 8] = mw;
        }
        // c[k][h] = cand_k · (Wa+Wd)[:,h] + B1[h]; 8 threads per h
        const int hc = tid >> 3, fgc = tid & 7;
        float wad[8];
        #pragma unroll
        for (int ff = 0; ff < 8; ++ff) {
            int f = fgc * 8 + ff;
            wad[ff] = W1[f * HID + hc] + W1[(3 * DIMV + f) * HID + hc];
        }
        float b1 = B1[hc];
        #pragma unroll
        for (int k = 0; k < NBPB; ++k) {
            const float* cb = cand + (size_t)(b0 + k) * DIMV + fgc * 8;
            float4 cA = *(const float4*)cb;
            float4 cB = *(const float4*)(cb + 4);
            float p = cA.x * wad[0] + cA.y * wad[1] + cA.z * wad[2] + cA.w * wad[3]
                    + cB.x * wad[4] + cB.y * wad[5] + cB.z * wad[6] + cB.w * wad[7];
            p = dpp_add<QXOR1>(p);
            p = dpp_add<QXOR2>(p);
            p = dpp_add<HMIRR>(p);
            if ((tid & 7) == 0) s_c[k][hc] = p + b1;
        }
    }
    __syncthreads();   // the only barrier

    // ---------------- per-wave flash loop over own batch ------------------------
    const int b    = b0 + wid;
    const int len  = lens[b];
    const bool uni = (len == 0);
    const int nrow = uni ? HS : len;          // len==0: uniform mean over all rows
    const int nt   = (nrow + 15) >> 4;
    const int lc   = lane & 15, lg = lane >> 4;
    const float* hb = hist + (size_t)b * (HS * DIMV);

    short8 b00 = *(const short8*)&s_Mt[wid][lc * 64        + ((lg)     ^ (lc & 7)) * 8];
    short8 b01 = *(const short8*)&s_Mt[wid][lc * 64        + ((4 + lg) ^ (lc & 7)) * 8];
    short8 b10 = *(const short8*)&s_Mt[wid][(16 + lc) * 64 + ((lg)     ^ (lc & 7)) * 8];
    short8 b11 = *(const short8*)&s_Mt[wid][(16 + lc) * 64 + ((4 + lg) ^ (lc & 7)) * 8];
    const float c0  = s_c[wid][lc],        c1  = s_c[wid][16 + lc];
    const float w20 = W2[lc] * 0.125f,     w21 = W2[16 + lc] * 0.125f;  // fold 1/sqrt(64)

    float m_run = -3.0e38f, l_acc = 0.f;
    float o0[8] = {0.f, 0.f, 0.f, 0.f, 0.f, 0.f, 0.f, 0.f};
    float o1[8] = {0.f, 0.f, 0.f, 0.f, 0.f, 0.f, 0.f, 0.f};

    for (int rt = 0; rt < nt; ++rt) {         // wave-uniform trip count
        int s = rt * 16 + lc;
        if (s > nrow - 1) s = nrow - 1;       // clamp (dup row; weight forced 0)
        const float* ap = hb + s * 64 + lg * 8;
        float4 A00 = *(const float4*)ap;
        float4 A01 = *(const float4*)(ap + 4);
        float4 A10 = *(const float4*)(ap + 32);
        float4 A11 = *(const float4*)(ap + 36);
        union { uint4 u; short8 s8; } u0, u1;
        u0.u = make_uint4(cvt2(A00.x, A00.y), cvt2(A00.z, A00.w),
                          cvt2(A01.x, A01.y), cvt2(A01.z, A01.w));
        u1.u = make_uint4(cvt2(A10.x, A10.y), cvt2(A10.z, A10.w),
                          cvt2(A11.x, A11.y), cvt2(A11.z, A11.w));

        f32x4 acc0 = {c0, c0, c0, c0};
        acc0 = __builtin_amdgcn_mfma_f32_16x16x32_bf16(u0.s8, b00, acc0, 0, 0, 0);
        acc0 = __builtin_amdgcn_mfma_f32_16x16x32_bf16(u1.s8, b01, acc0, 0, 0, 0);
        f32x4 acc1 = {c1, c1, c1, c1};
        acc1 = __builtin_amdgcn_mfma_f32_16x16x32_bf16(u0.s8, b10, acc1, 0, 0, 0);
        acc1 = __builtin_amdgcn_mfma_f32_16x16x32_bf16(u1.s8, b11, acc1, 0, 0, 0);

        float p[4];
        #pragma unroll
        for (int r = 0; r < 4; ++r)
            p[r] = fmaxf(acc0[r], 0.f) * w20 + fmaxf(acc1[r], 0.f) * w21;  // scaled score
        #pragma unroll
        for (int r = 0; r < 4; ++r) {         // cyclic 16-lane reduce: ALL lanes get sum
            p[r] = dpp_add<ROR1>(p[r]);
            p[r] = dpp_add<ROR2>(p[r]);
            p[r] = dpp_add<ROR4>(p[r]);
            p[r] = dpp_add<ROR8>(p[r]);
        }
        #pragma unroll
        for (int r = 0; r < 4; ++r) {         // mask + uniform override
            int row = rt * 16 + lg * 4 + r;
            p[r] = (row < nrow) ? (uni ? 0.f : p[r]) : -4.0e9f;
        }
        float tmax = fmaxf(fmaxf(p[0], p[1]), fmaxf(p[2], p[3]));
        tmax = fmaxf(tmax, swz_xor16(tmax));
        tmax = fmaxf(tmax, __shfl_xor(tmax, 32));
        tmax = rfl(tmax);                     // exec-uniform running max decision
        if (tmax > m_run + 8.f) {             // T13 defer-rescale
            float sf = __expf(m_run - tmax);  // first tile: exp(-inf) = 0
            #pragma unroll
            for (int j = 0; j < 8; ++j) { o0[j] *= sf; o1[j] *= sf; }
            l_acc *= sf;
            m_run = tmax;
        }
        float e[4];
        #pragma unroll
        for (int r = 0; r < 4; ++r) e[r] = __expf(p[r] - m_run);  // masked -> 0
        l_acc += (e[0] + e[1]) + (e[2] + e[3]);

        // weight for THIS lane's row (row = rt*16+lc): select e[lc&3], pull from
        // lane (lc&3) + 16*(lc>>2)  [any lc_src with lc_src&3 == lc&3 works]
        float t0 = (lc & 1) ? e[1] : e[0];
        float t1 = (lc & 1) ? e[3] : e[2];
        float es = (lc & 2) ? t1 : t0;
        int   src = (((lc & 3) | ((lc >> 2) << 4)) << 2);
        float wrow = __int_as_float(
            __builtin_amdgcn_ds_bpermute(src, __float_as_int(es)));

        o0[0] = fmaf(wrow, A00.x, o0[0]); o0[1] = fmaf(wrow, A00.y, o0[1]);
        o0[2] = fmaf(wrow, A00.z, o0[2]); o0[3] = fmaf(wrow, A00.w, o0[3]);
        o0[4] = fmaf(wrow, A01.x, o0[4]); o0[5] = fmaf(wrow, A01.y, o0[5]);
        o0[6] = fmaf(wrow, A01.z, o0[6]); o0[7] = fmaf(wrow, A01.w, o0[7]);
        o1[0] = fmaf(wrow, A10.x, o1[0]); o1[1] = fmaf(wrow, A10.y, o1[1]);
        o1[2] = fmaf(wrow, A10.z, o1[2]); o1[3] = fmaf(wrow, A10.w, o1[3]);
        o1[4] = fmaf(wrow, A11.x, o1[4]); o1[5] = fmaf(wrow, A11.y, o1[5]);
        o1[6] = fmaf(wrow, A11.z, o1[6]); o1[7] = fmaf(wrow, A11.w, o1[7]);
    }

    // ---------------- finalize: den over lg; o over the 16 rows (lc) ------------
    l_acc += swz_xor16(l_acc);
    l_acc += __shfl_xor(l_acc, 32);
    const float inv = 1.0f / l_acc;
    #pragma unroll
    for (int j = 0; j < 8; ++j) {
        float x = o0[j];
        x = dpp_add<ROR1>(x); x = dpp_add<ROR2>(x);
        x = dpp_add<ROR4>(x); x = dpp_add<ROR8>(x);
        o0[j] = x * inv;
        float y = o1[j];
        y = dpp_add<ROR1>(y); y = dpp_add<ROR2>(y);
        y = dpp_add<ROR4>(y); y = dpp_add<ROR8>(y);
        o1[j] = y * inv;
    }
    if (lc == 0) {                            // lanes 0,16,32,48: d = lg*8.. & 32+lg*8..
        float* op = out + (size_t)b * DIMV + lg * 8;
        *(float4*)op        = make_float4(o0[0], o0[1], o0[2], o0[3]);
        *(float4*)(op + 4)  = make_float4(o0[4], o0[5], o0[6], o0[7]);
        *(float4*)(op + 32) = make_float4(o1[0], o1[1], o1[2], o1[3]);
        *(float4*)(op + 36) = make_float4(o1[4], o1[5], o1[6], o1[7]);
    }
}

extern "C" void kernel_launch(void* const* d_in, const int* in_sizes, int n_in,
                              void* d_out, int out_size, void* d_ws, size_t ws_size,
                              hipStream_t stream) {
    const float* cand = (const float*)d_in[0];
    const float* hist = (const float*)d_in[1];
    const int*   lens = (const int*)d_in[2];
    const float* W1   = (const float*)d_in[3];
    const float* B1   = (const float*)d_in[4];
    const float* W2   = (const float*)d_in[5];
    const float* B2   = (const float*)d_in[6];
    float* out = (float*)d_out;

    const int B = in_sizes[0] / DIMV;     // 4096
    const int GRID = B / NBPB;            // 1024 blocks x 4 waves = 4096 waves
    din_attn_kernel<<<GRID, NTH, 0, stream>>>(cand, hist, lens, W1, B1, W2, B2, out);
}